// Round 3
// baseline (184.281 us; speedup 1.0000x reference)
//
#include <hip/hip_runtime.h>
#include <hip/hip_bf16.h>
#include <math.h>

// Problem constants (reference: B,S,H,L = 16,128,512,43)
#define BB 16
#define SS 128
#define HH 512
#define LL 43
#define NEGV -10000.0f
#define M_TOT (BB*SS)   // 2048

#define LOG2E 1.44269504088896f
#define TWO_LOG2E 2.88539008177793f
#define LN2 0.69314718055995f

__device__ __forceinline__ float fast_exp2(float x) { return __builtin_amdgcn_exp2f(x); }
__device__ __forceinline__ float fast_rcp(float x)  { return __builtin_amdgcn_rcpf(x); }
__device__ __forceinline__ float fast_log2(float x) { return __builtin_amdgcn_logf(x); }
__device__ __forceinline__ float exp_fast(float x)  { return fast_exp2(x * LOG2E); }

// Input already prescaled by 2*log2(e):  tanh(x) == 1 - 2/(1 + 2^{x'})
__device__ __forceinline__ float tanh_pre(float xp) {
    float e = fast_exp2(xp);
    return fmaf(-2.0f, fast_rcp(e + 1.0f), 1.0f);
}

// ------------------------------------------------------------------
// Kernel 1 (v3): in-block split-K fused GEMM.
//   u'[m][n] = (repr[m]·u_w[:512,n] + u_b[n]) * 2log2e
//   w'[m][n] = (repr[m]·w_w[:512,n] + labels[m]·w_w[512:,n] + w_b[n]) * 2log2e
// 256 blocks (tile 64x64, both outputs), 512 threads = 2 k-groups of 256.
//   group 0: repr k in [0,272)            -> 17 iters + 1 dummy = 18
//   group 1: repr k in [272,512) + labels -> 15 + 3 = 18 iters
// Equal iteration counts keep block-wide __syncthreads legal.
// Partial accumulators merged via LDS epilogue (union-aliased).
// Occupancy: 8 waves/block, 1 block/CU -> 2 waves/SIMD (was 1).
// As padded to stride 68 floats: 16B-aligned ds_read_b128, <=2-way store banks.
// ------------------------------------------------------------------
#define BM 64
#define BN 64
#define BK 16
#define KSPLIT 272
#define NIT 18

union GemmShared {
    struct {
        float As[2][BK][BM + 4];   // stride 68: 16B aligned, conflict-free-ish
        float Bu[2][BK][BN];
        float Bw[2][BK][BN];
    } t;
    float epi[BM][BN + 4];         // epilogue staging (17.4KB <= tile bytes)
};

__global__ __launch_bounds__(512)
void gemm_uw_v3(const float* __restrict__ repr, const float* __restrict__ labels,
                const float* __restrict__ u_w, const float* __restrict__ u_b,
                const float* __restrict__ w_w, const float* __restrict__ w_b,
                float* __restrict__ u_out, float* __restrict__ w_out) {
    __shared__ GemmShared sh;

    const int tid = threadIdx.x;
    const int gid = tid >> 8;                 // k-split group: 0 or 1
    const int t   = tid & 255;                // id within group
    const int bm  = blockIdx.x & 31;
    const int bn  = blockIdx.x >> 5;
    const int m0  = bm * BM;
    const int n0  = bn * BN;

    const int ty = t >> 4;                    // 0..15
    const int tx = t & 15;                    // 0..15

    const int arow = t >> 2;                  // 0..63
    const int acol = (t & 3) << 2;            // 0,4,8,12 (k within tile)
    const int bkr  = t >> 4;                  // 0..15 (k row)
    const int bcol = (t & 15) << 2;           // 0..60

    float acc_u[4][4] = {};
    float acc_w[4][4] = {};

    for (int it = 0; it < NIT; ++it) {
        float a[4];
        float4 bu, bw;
        if (gid == 0) {
            if (it < 17) {
                const int k0 = it * BK;
                float4 av = *(const float4*)&repr[(size_t)(m0 + arow) * HH + k0 + acol];
                a[0] = av.x; a[1] = av.y; a[2] = av.z; a[3] = av.w;
                bu = *(const float4*)&u_w[(size_t)(k0 + bkr) * HH + n0 + bcol];
                bw = *(const float4*)&w_w[(size_t)(k0 + bkr) * HH + n0 + bcol];
            } else {                           // dummy iter: zeros
                a[0] = a[1] = a[2] = a[3] = 0.f;
                bu = make_float4(0.f, 0.f, 0.f, 0.f);
                bw = make_float4(0.f, 0.f, 0.f, 0.f);
            }
        } else {
            if (it < 15) {                     // repr k in [272,512)
                const int k0 = KSPLIT + it * BK;
                float4 av = *(const float4*)&repr[(size_t)(m0 + arow) * HH + k0 + acol];
                a[0] = av.x; a[1] = av.y; a[2] = av.z; a[3] = av.w;
                bu = *(const float4*)&u_w[(size_t)(k0 + bkr) * HH + n0 + bcol];
                bw = *(const float4*)&w_w[(size_t)(k0 + bkr) * HH + n0 + bcol];
            } else {                           // labels k in [0,48) guarded to 43
                const int k0 = (it - 15) * BK;
#pragma unroll
                for (int q = 0; q < 4; ++q) {
                    const int k = k0 + acol + q;
                    a[q] = (k < LL) ? labels[(size_t)(m0 + arow) * LL + k] : 0.f;
                }
                bu = make_float4(0.f, 0.f, 0.f, 0.f);   // u: no label contribution
                const int k = k0 + bkr;
                if (k < LL) bw = *(const float4*)&w_w[(size_t)(HH + k) * HH + n0 + bcol];
                else        bw = make_float4(0.f, 0.f, 0.f, 0.f);
            }
        }

        sh.t.As[gid][acol + 0][arow] = a[0];
        sh.t.As[gid][acol + 1][arow] = a[1];
        sh.t.As[gid][acol + 2][arow] = a[2];
        sh.t.As[gid][acol + 3][arow] = a[3];
        *(float4*)&sh.t.Bu[gid][bkr][bcol] = bu;
        *(float4*)&sh.t.Bw[gid][bkr][bcol] = bw;
        __syncthreads();

#pragma unroll
        for (int k = 0; k < BK; ++k) {
            float4 av = *(const float4*)&sh.t.As[gid][k][ty << 2];
            float4 fu = *(const float4*)&sh.t.Bu[gid][k][tx << 2];
            float4 fw = *(const float4*)&sh.t.Bw[gid][k][tx << 2];
            const float ar[4] = {av.x, av.y, av.z, av.w};
            const float ur[4] = {fu.x, fu.y, fu.z, fu.w};
            const float wr[4] = {fw.x, fw.y, fw.z, fw.w};
#pragma unroll
            for (int i = 0; i < 4; ++i)
#pragma unroll
                for (int j = 0; j < 4; ++j) {
                    acc_u[i][j] = fmaf(ar[i], ur[j], acc_u[i][j]);
                    acc_w[i][j] = fmaf(ar[i], wr[j], acc_w[i][j]);
                }
        }
        __syncthreads();
    }

    // ---- epilogue: merge group partials via LDS, add bias, prescale ----
    // (tile buffers dead now; epi aliases them via union)
    if (gid == 1) {
#pragma unroll
        for (int i = 0; i < 4; ++i)
            *(float4*)&sh.epi[(ty << 2) + i][tx << 2] = *(float4*)&acc_u[i][0];
    }
    __syncthreads();
    if (gid == 0) {
        const int c = n0 + (tx << 2);
        float4 ub = *(const float4*)&u_b[c];
#pragma unroll
        for (int i = 0; i < 4; ++i) {
            const int r = m0 + (ty << 2) + i;
            float4 p = *(float4*)&sh.epi[(ty << 2) + i][tx << 2];
            float4 o;
            o.x = (acc_u[i][0] + p.x + ub.x) * TWO_LOG2E;
            o.y = (acc_u[i][1] + p.y + ub.y) * TWO_LOG2E;
            o.z = (acc_u[i][2] + p.z + ub.z) * TWO_LOG2E;
            o.w = (acc_u[i][3] + p.w + ub.w) * TWO_LOG2E;
            *(float4*)&u_out[(size_t)r * HH + c] = o;
        }
    }
    __syncthreads();
    if (gid == 1) {
#pragma unroll
        for (int i = 0; i < 4; ++i)
            *(float4*)&sh.epi[(ty << 2) + i][tx << 2] = *(float4*)&acc_w[i][0];
    }
    __syncthreads();
    if (gid == 0) {
        const int c = n0 + (tx << 2);
        float4 wb = *(const float4*)&w_b[c];
#pragma unroll
        for (int i = 0; i < 4; ++i) {
            const int r = m0 + (ty << 2) + i;
            float4 p = *(float4*)&sh.epi[(ty << 2) + i][tx << 2];
            float4 o;
            o.x = (acc_w[i][0] + p.x + wb.x) * TWO_LOG2E;
            o.y = (acc_w[i][1] + p.y + wb.y) * TWO_LOG2E;
            o.z = (acc_w[i][2] + p.z + wb.z) * TWO_LOG2E;
            o.w = (acc_w[i][3] + p.w + wb.w) * TWO_LOG2E;
            *(float4*)&w_out[(size_t)r * HH + c] = o;
        }
    }
}

// ------------------------------------------------------------------
// Kernel 2 (v2, UNCHANGED this round): j-as-lane scores.
// ------------------------------------------------------------------
__global__ __launch_bounds__(256)
void scores_v2(const float* __restrict__ u, const float* __restrict__ w,
               const float* __restrict__ v_w, const int* __restrict__ heads,
               const int* __restrict__ words,
               float* __restrict__ out,      // [0]=loss (kernel 3), [1..] probs
               float* __restrict__ ce_out) {
    const int blk = blockIdx.x;               // 0..511
    const int r   = blk & 7;
    const int q   = blk >> 3;                 // 0..63
    const int b   = r * 2 + (q & 1);
    const int i0  = (q >> 1) * 4;             // 4 i-rows per block

    const int tid  = threadIdx.x;
    const int wv   = tid >> 6;                // 0..3
    const int lane = tid & 63;
    const int ig   = wv >> 1;                 // i-pair select
    const int jh   = wv & 1;                  // j-half select
    const int j    = jh * 64 + lane;
    const int ia   = i0 + ig * 2;             // first i-row of this wave

    const float* __restrict__ up  = &u[(size_t)(b * SS + j) * HH];
    const float* __restrict__ w0p = &w[(size_t)(b * SS + ia) * HH];
    const float* __restrict__ w1p = w0p + HH;

    float acc0 = 0.f, acc1 = 0.f;
#pragma unroll 2
    for (int h = 0; h < HH; h += 8) {
        float4 ua = *(const float4*)&up[h];
        float4 ub = *(const float4*)&up[h + 4];
        float4 va = *(const float4*)&v_w[h];      // uniform -> s_load
        float4 vb = *(const float4*)&v_w[h + 4];
        float4 w0a = *(const float4*)&w0p[h];     // uniform -> s_load
        float4 w0b = *(const float4*)&w0p[h + 4];
        float4 w1a = *(const float4*)&w1p[h];
        float4 w1b = *(const float4*)&w1p[h + 4];
#define STEP(UU, VV, W0, W1)                                  \
        acc0 = fmaf(VV, tanh_pre(UU + W0), acc0);             \
        acc1 = fmaf(VV, tanh_pre(UU + W1), acc1);
        STEP(ua.x, va.x, w0a.x, w1a.x)
        STEP(ua.y, va.y, w0a.y, w1a.y)
        STEP(ua.z, va.z, w0a.z, w1a.z)
        STEP(ua.w, va.w, w0a.w, w1a.w)
        STEP(ub.x, vb.x, w0b.x, w1b.x)
        STEP(ub.y, vb.y, w0b.y, w1b.y)
        STEP(ub.z, vb.z, w0b.z, w1b.z)
        STEP(ub.w, vb.w, w0b.w, w1b.w)
#undef STEP
    }

    // ---- masks (column mask identical for both i rows) ----
    const bool colpad = (words[b * SS + j] == 0);
    float s0 = (colpad || j == ia)     ? NEGV : acc0;
    float s1 = (colpad || j == ia + 1) ? NEGV : acc1;

    __shared__ float s_lds[4][SS];
    s_lds[ig * 2 + 0][j] = s0;
    s_lds[ig * 2 + 1][j] = s1;

    // ---- probs = exp(masked scores), rows i>=1 only ----
    if (ia >= 1)
        out[1 + (size_t)(b * (SS - 1) + (ia - 1)) * SS + j] = exp_fast(s0);
    out[1 + (size_t)(b * (SS - 1) + ia) * SS + j] = exp_fast(s1);

    __syncthreads();

    // ---- softmax + CE: wave wv handles row i0+wv ----
    const int i  = i0 + wv;
    float t0 = s_lds[wv][lane];
    float t1 = s_lds[wv][lane + 64];
    float m = fmaxf(t0, t1);
#pragma unroll
    for (int off = 32; off > 0; off >>= 1) m = fmaxf(m, __shfl_xor(m, off));
    float e = exp_fast(t0 - m) + exp_fast(t1 - m);
#pragma unroll
    for (int off = 32; off > 0; off >>= 1) e += __shfl_xor(e, off);

    const int hd = heads[b * SS + i];
    const float sh = s_lds[wv][hd];           // masked score at head
    const float ce = m + fast_log2(e) * LN2 - sh;
    if (lane == 0) ce_out[b * SS + i] = (i >= 1) ? ce : 0.f;
}

// ------------------------------------------------------------------
// Kernel 3: deterministic loss reduction (f64 accumulate)
// ------------------------------------------------------------------
__global__ __launch_bounds__(256)
void loss_sum(const float* __restrict__ ce, float* __restrict__ out) {
    __shared__ double sd[256];
    const int tid = threadIdx.x;
    double s = 0.0;
    for (int k = tid; k < M_TOT; k += 256) s += (double)ce[k];
    sd[tid] = s;
    __syncthreads();
    for (int off = 128; off > 0; off >>= 1) {
        if (tid < off) sd[tid] += sd[tid + off];
        __syncthreads();
    }
    if (tid == 0) out[0] = (float)(sd[0] * (1.0 / (double)BB));
}

// ------------------------------------------------------------------
extern "C" void kernel_launch(void* const* d_in, const int* in_sizes, int n_in,
                              void* d_out, int out_size, void* d_ws, size_t ws_size,
                              hipStream_t stream) {
    const float* repr   = (const float*)d_in[0];   // [16,128,512]
    const float* labels = (const float*)d_in[1];   // [16,128,43]
    const int*   heads  = (const int*)d_in[2];     // [16,128]
    const int*   words  = (const int*)d_in[3];     // [16,128]
    // d_in[4] = sent_id (unused)
    const float* u_w    = (const float*)d_in[5];   // [555,512]
    const float* u_b    = (const float*)d_in[6];   // [512]
    const float* w_w    = (const float*)d_in[7];   // [555,512]
    const float* w_b    = (const float*)d_in[8];   // [512]
    const float* v_w    = (const float*)d_in[9];   // [512,1]

    float* out = (float*)d_out;                    // [0]=loss, rest probs [16,127,128]

    float* u_ws  = (float*)d_ws;                   // 2048*512 floats = 4 MB (prescaled)
    float* w_ws  = u_ws + (size_t)M_TOT * HH;      // 4 MB (prescaled)
    float* ce_ws = w_ws + (size_t)M_TOT * HH;      // 2048 floats

    gemm_uw_v3<<<dim3(256), dim3(512), 0, stream>>>(repr, labels, u_w, u_b, w_w, w_b,
                                                    u_ws, w_ws);
    scores_v2<<<dim3(512), dim3(256), 0, stream>>>(
        u_ws, w_ws, v_w, heads, words, out, ce_ws);
    loss_sum<<<dim3(1), dim3(256), 0, stream>>>(ce_ws, out);
}

// Round 4
// 146.959 us; speedup vs baseline: 1.2540x; 1.2540x over previous
//
#include <hip/hip_runtime.h>
#include <hip/hip_bf16.h>
#include <math.h>

// Problem constants (reference: B,S,H,L = 16,128,512,43)
#define BB 16
#define SS 128
#define HH 512
#define LL 43
#define NEGV -10000.0f
#define M_TOT (BB*SS)   // 2048
#define KP 576          // padded K (512 repr + 43 labels + 21 zero), 18 tiles of 32

#define LOG2E 1.44269504088896f
#define TWO_LOG2E 2.88539008177793f
#define LN2 0.69314718055995f

typedef __bf16 bf16_t;
typedef __attribute__((ext_vector_type(8)))  __bf16 bf16x8;
typedef __attribute__((ext_vector_type(16))) float  f32x16;

__device__ __forceinline__ float fast_exp2(float x) { return __builtin_amdgcn_exp2f(x); }
__device__ __forceinline__ float fast_rcp(float x)  { return __builtin_amdgcn_rcpf(x); }
__device__ __forceinline__ float fast_log2(float x) { return __builtin_amdgcn_logf(x); }
__device__ __forceinline__ float exp_fast(float x)  { return fast_exp2(x * LOG2E); }

// Input already prescaled by 2*log2(e):  tanh(x) == 1 - 2/(1 + 2^{x'})
__device__ __forceinline__ float tanh_pre(float xp) {
    float e = fast_exp2(xp);
    return fmaf(-2.0f, fast_rcp(e + 1.0f), 1.0f);
}

// ------------------------------------------------------------------
// Kernel 0: split fp32 -> bf16 hi/lo workspace buffers.
//  blocks [0,288):  weight transpose+split tiles (32x32):
//     Btu_{h,l}[n][k] = split(k<512 ? u_w[k][n] : 0)      n in [0,512), k in [0,576)
//     Btw_{h,l}[n][k] = split(k<555 ? w_w[k][n] : 0)
//  blocks [288,1440): A split (row-major, 4-elem chunks):
//     Afull[m][k] = k<512 ? repr[m][k] : (k<555 ? labels[m][k-512] : 0)
// ------------------------------------------------------------------
__global__ __launch_bounds__(256)
void split_kernel(const float* __restrict__ repr, const float* __restrict__ labels,
                  const float* __restrict__ u_w, const float* __restrict__ w_w,
                  bf16_t* __restrict__ Ah, bf16_t* __restrict__ Al,
                  bf16_t* __restrict__ Buh, bf16_t* __restrict__ Bul,
                  bf16_t* __restrict__ Bwh, bf16_t* __restrict__ Bwl) {
    const int tid = threadIdx.x;
    if (blockIdx.x < 288) {
        // ---- weight transpose tiles ----
        const int kt = blockIdx.x >> 4;        // 0..17
        const int nt = blockIdx.x & 15;        // 0..15
        const int k0 = kt * 32, n0 = nt * 32;
        __shared__ float tu[32][33], tw[32][33];
        {
            const int r  = tid >> 3;           // 0..31 (k-row in tile)
            const int c4 = (tid & 7) << 2;     // 0..28 (n-col chunk)
            const int k  = k0 + r;
            float4 fu = make_float4(0.f, 0.f, 0.f, 0.f);
            float4 fw = make_float4(0.f, 0.f, 0.f, 0.f);
            if (k < HH)      fu = *(const float4*)&u_w[(size_t)k * HH + n0 + c4];
            if (k < HH + LL) fw = *(const float4*)&w_w[(size_t)k * HH + n0 + c4];
            tu[r][c4+0] = fu.x; tu[r][c4+1] = fu.y; tu[r][c4+2] = fu.z; tu[r][c4+3] = fu.w;
            tw[r][c4+0] = fw.x; tw[r][c4+1] = fw.y; tw[r][c4+2] = fw.z; tw[r][c4+3] = fw.w;
        }
        __syncthreads();
        {
            const int nr = tid >> 3;           // 0..31 (n-row of Bt)
            const int k4 = (tid & 7) << 2;     // 0..28 (k chunk)
            union { bf16_t h[4]; uint2 v; } uh, ul, wh, wl;
#pragma unroll
            for (int q = 0; q < 4; ++q) {
                float xu = tu[k4 + q][nr];
                float xw = tw[k4 + q][nr];
                bf16_t hu = (bf16_t)xu; bf16_t lu = (bf16_t)(xu - (float)hu);
                bf16_t hw = (bf16_t)xw; bf16_t lw = (bf16_t)(xw - (float)hw);
                uh.h[q] = hu; ul.h[q] = lu; wh.h[q] = hw; wl.h[q] = lw;
            }
            const size_t o = (size_t)(n0 + nr) * KP + k0 + k4;
            *(uint2*)&Buh[o] = uh.v;  *(uint2*)&Bul[o] = ul.v;
            *(uint2*)&Bwh[o] = wh.v;  *(uint2*)&Bwl[o] = wl.v;
        }
    } else {
        // ---- A split: chunk = 4 consecutive k of one m-row ----
        const int chunk = (blockIdx.x - 288) * 256 + tid;   // 0..294911
        const int m  = chunk / 144;                         // KP/4 = 144 chunks per row
        const int c4 = chunk - m * 144;
        const int k  = c4 << 2;
        float x[4];
        if (k <= HH - 4) {
            float4 f = *(const float4*)&repr[(size_t)m * HH + k];
            x[0] = f.x; x[1] = f.y; x[2] = f.z; x[3] = f.w;
        } else {            // k >= 512 here (chunks are 4-aligned, 512 % 4 == 0)
#pragma unroll
            for (int q = 0; q < 4; ++q) {
                const int kk = k + q;
                x[q] = (kk < HH + LL) ? labels[(size_t)m * LL + (kk - HH)] : 0.f;
            }
        }
        union { bf16_t h[4]; uint2 v; } ph, pl;
#pragma unroll
        for (int q = 0; q < 4; ++q) {
            bf16_t hi = (bf16_t)x[q];
            ph.h[q] = hi;
            pl.h[q] = (bf16_t)(x[q] - (float)hi);
        }
        const size_t o = (size_t)m * KP + k;
        *(uint2*)&Ah[o] = ph.v;
        *(uint2*)&Al[o] = pl.v;
    }
}

// ------------------------------------------------------------------
// Kernel 1 (v4): MFMA GEMM, bf16 hi/lo 3-pass (hh + hl + lh).
// 256 blocks: tile 64x64 of BOTH u and w.  256 thr = 4 waves (2x2 of 32x32).
// mfma_f32_32x32x16_bf16; k-bijection f(g,e)=g*8+e used identically for A
// and B fragments (any consistent bijection is exact).  C/D layout per
// m74/m101: n=lane&31, m=(reg&3)+8*(reg>>2)+4*(lane>>5).
// LDS tiles stride 40 bf16 (80B): b128 reads/writes uniform over bank-quads.
// ------------------------------------------------------------------
__global__ __launch_bounds__(256)
void gemm_mfma(const bf16_t* __restrict__ Ah, const bf16_t* __restrict__ Al,
               const bf16_t* __restrict__ Buh, const bf16_t* __restrict__ Bul,
               const bf16_t* __restrict__ Bwh, const bf16_t* __restrict__ Bwl,
               const float* __restrict__ u_b, const float* __restrict__ w_b,
               float* __restrict__ u_out, float* __restrict__ w_out) {
    __shared__ bf16_t sm[6][64][40];    // Ah,Al,Buh,Bul,Bwh,Bwl tiles

    const int tid  = threadIdx.x;
    const int bm   = blockIdx.x & 31;
    const int bn   = blockIdx.x >> 5;
    const int m0   = bm * 64, n0 = bn * 64;
    const int wv   = tid >> 6, lane = tid & 63;
    const int wm   = wv >> 1, wn = wv & 1;
    const int ln31 = lane & 31, g = lane >> 5;

    const int sr = tid >> 2;            // stage row 0..63
    const int sc = tid & 3;             // stage 16B chunk 0..3

    f32x16 accu = {0,0,0,0,0,0,0,0,0,0,0,0,0,0,0,0};
    f32x16 accw = {0,0,0,0,0,0,0,0,0,0,0,0,0,0,0,0};

    const size_t aoff = (size_t)(m0 + sr) * KP;
    const size_t boff = (size_t)(n0 + sr) * KP;

    for (int kt = 0; kt < KP / 32; ++kt) {
        const int kc = kt * 32 + sc * 8;          // global k elem of this chunk
        *(uint4*)&sm[0][sr][sc * 8] = *(const uint4*)&Ah [aoff + kc];
        *(uint4*)&sm[1][sr][sc * 8] = *(const uint4*)&Al [aoff + kc];
        *(uint4*)&sm[2][sr][sc * 8] = *(const uint4*)&Buh[boff + kc];
        *(uint4*)&sm[3][sr][sc * 8] = *(const uint4*)&Bul[boff + kc];
        *(uint4*)&sm[4][sr][sc * 8] = *(const uint4*)&Bwh[boff + kc];
        *(uint4*)&sm[5][sr][sc * 8] = *(const uint4*)&Bwl[boff + kc];
        __syncthreads();

#pragma unroll
        for (int ks = 0; ks < 2; ++ks) {
            const int co = ks * 16 + g * 8;       // k-frag col in LDS tile
            bf16x8 a_h = *(const bf16x8*)&sm[0][wm * 32 + ln31][co];
            bf16x8 a_l = *(const bf16x8*)&sm[1][wm * 32 + ln31][co];
            bf16x8 buh = *(const bf16x8*)&sm[2][wn * 32 + ln31][co];
            bf16x8 bul = *(const bf16x8*)&sm[3][wn * 32 + ln31][co];
            bf16x8 bwh = *(const bf16x8*)&sm[4][wn * 32 + ln31][co];
            bf16x8 bwl = *(const bf16x8*)&sm[5][wn * 32 + ln31][co];
            accu = __builtin_amdgcn_mfma_f32_32x32x16_bf16(a_h, buh, accu, 0, 0, 0);
            accu = __builtin_amdgcn_mfma_f32_32x32x16_bf16(a_h, bul, accu, 0, 0, 0);
            accu = __builtin_amdgcn_mfma_f32_32x32x16_bf16(a_l, buh, accu, 0, 0, 0);
            accw = __builtin_amdgcn_mfma_f32_32x32x16_bf16(a_h, bwh, accw, 0, 0, 0);
            accw = __builtin_amdgcn_mfma_f32_32x32x16_bf16(a_h, bwl, accw, 0, 0, 0);
            accw = __builtin_amdgcn_mfma_f32_32x32x16_bf16(a_l, bwh, accw, 0, 0, 0);
        }
        __syncthreads();
    }

    // ---- epilogue: bias + prescale, direct global stores ----
    const int C = n0 + wn * 32 + ln31;
    const float ub = u_b[C], wb = w_b[C];
#pragma unroll
    for (int rg = 0; rg < 16; ++rg) {
        const int m = (rg & 3) + 8 * (rg >> 2) + 4 * g;
        const int R = m0 + wm * 32 + m;
        u_out[(size_t)R * HH + C] = (accu[rg] + ub) * TWO_LOG2E;
        w_out[(size_t)R * HH + C] = (accw[rg] + wb) * TWO_LOG2E;
    }
}

// ------------------------------------------------------------------
// Kernel 2 (v2, UNCHANGED): j-as-lane scores.
// ------------------------------------------------------------------
__global__ __launch_bounds__(256)
void scores_v2(const float* __restrict__ u, const float* __restrict__ w,
               const float* __restrict__ v_w, const int* __restrict__ heads,
               const int* __restrict__ words,
               float* __restrict__ out,      // [0]=loss (kernel 3), [1..] probs
               float* __restrict__ ce_out) {
    const int blk = blockIdx.x;               // 0..511
    const int r   = blk & 7;
    const int q   = blk >> 3;                 // 0..63
    const int b   = r * 2 + (q & 1);
    const int i0  = (q >> 1) * 4;             // 4 i-rows per block

    const int tid  = threadIdx.x;
    const int wv   = tid >> 6;                // 0..3
    const int lane = tid & 63;
    const int ig   = wv >> 1;                 // i-pair select
    const int jh   = wv & 1;                  // j-half select
    const int j    = jh * 64 + lane;
    const int ia   = i0 + ig * 2;             // first i-row of this wave

    const float* __restrict__ up  = &u[(size_t)(b * SS + j) * HH];
    const float* __restrict__ w0p = &w[(size_t)(b * SS + ia) * HH];
    const float* __restrict__ w1p = w0p + HH;

    float acc0 = 0.f, acc1 = 0.f;
#pragma unroll 2
    for (int h = 0; h < HH; h += 8) {
        float4 ua = *(const float4*)&up[h];
        float4 ub = *(const float4*)&up[h + 4];
        float4 va = *(const float4*)&v_w[h];      // uniform -> s_load
        float4 vb = *(const float4*)&v_w[h + 4];
        float4 w0a = *(const float4*)&w0p[h];     // uniform -> s_load
        float4 w0b = *(const float4*)&w0p[h + 4];
        float4 w1a = *(const float4*)&w1p[h];
        float4 w1b = *(const float4*)&w1p[h + 4];
#define STEP(UU, VV, W0, W1)                                  \
        acc0 = fmaf(VV, tanh_pre(UU + W0), acc0);             \
        acc1 = fmaf(VV, tanh_pre(UU + W1), acc1);
        STEP(ua.x, va.x, w0a.x, w1a.x)
        STEP(ua.y, va.y, w0a.y, w1a.y)
        STEP(ua.z, va.z, w0a.z, w1a.z)
        STEP(ua.w, va.w, w0a.w, w1a.w)
        STEP(ub.x, vb.x, w0b.x, w1b.x)
        STEP(ub.y, vb.y, w0b.y, w1b.y)
        STEP(ub.z, vb.z, w0b.z, w1b.z)
        STEP(ub.w, vb.w, w0b.w, w1b.w)
#undef STEP
    }

    // ---- masks (column mask identical for both i rows) ----
    const bool colpad = (words[b * SS + j] == 0);
    float s0 = (colpad || j == ia)     ? NEGV : acc0;
    float s1 = (colpad || j == ia + 1) ? NEGV : acc1;

    __shared__ float s_lds[4][SS];
    s_lds[ig * 2 + 0][j] = s0;
    s_lds[ig * 2 + 1][j] = s1;

    // ---- probs = exp(masked scores), rows i>=1 only ----
    if (ia >= 1)
        out[1 + (size_t)(b * (SS - 1) + (ia - 1)) * SS + j] = exp_fast(s0);
    out[1 + (size_t)(b * (SS - 1) + ia) * SS + j] = exp_fast(s1);

    __syncthreads();

    // ---- softmax + CE: wave wv handles row i0+wv ----
    const int i  = i0 + wv;
    float t0 = s_lds[wv][lane];
    float t1 = s_lds[wv][lane + 64];
    float m = fmaxf(t0, t1);
#pragma unroll
    for (int off = 32; off > 0; off >>= 1) m = fmaxf(m, __shfl_xor(m, off));
    float e = exp_fast(t0 - m) + exp_fast(t1 - m);
#pragma unroll
    for (int off = 32; off > 0; off >>= 1) e += __shfl_xor(e, off);

    const int hd = heads[b * SS + i];
    const float sh = s_lds[wv][hd];           // masked score at head
    const float ce = m + fast_log2(e) * LN2 - sh;
    if (lane == 0) ce_out[b * SS + i] = (i >= 1) ? ce : 0.f;
}

// ------------------------------------------------------------------
// Kernel 3: deterministic loss reduction (f64 accumulate)
// ------------------------------------------------------------------
__global__ __launch_bounds__(256)
void loss_sum(const float* __restrict__ ce, float* __restrict__ out) {
    __shared__ double sd[256];
    const int tid = threadIdx.x;
    double s = 0.0;
    for (int k = tid; k < M_TOT; k += 256) s += (double)ce[k];
    sd[tid] = s;
    __syncthreads();
    for (int off = 128; off > 0; off >>= 1) {
        if (tid < off) sd[tid] += sd[tid + off];
        __syncthreads();
    }
    if (tid == 0) out[0] = (float)(sd[0] * (1.0 / (double)BB));
}

// ------------------------------------------------------------------
extern "C" void kernel_launch(void* const* d_in, const int* in_sizes, int n_in,
                              void* d_out, int out_size, void* d_ws, size_t ws_size,
                              hipStream_t stream) {
    const float* repr   = (const float*)d_in[0];   // [16,128,512]
    const float* labels = (const float*)d_in[1];   // [16,128,43]
    const int*   heads  = (const int*)d_in[2];     // [16,128]
    const int*   words  = (const int*)d_in[3];     // [16,128]
    // d_in[4] = sent_id (unused)
    const float* u_w    = (const float*)d_in[5];   // [555,512]
    const float* u_b    = (const float*)d_in[6];   // [512]
    const float* w_w    = (const float*)d_in[7];   // [555,512]
    const float* w_b    = (const float*)d_in[8];   // [512]
    const float* v_w    = (const float*)d_in[9];   // [512,1]

    float* out = (float*)d_out;                    // [0]=loss, rest probs [16,127,128]

    // ---- workspace layout (bytes) ----
    char* ws = (char*)d_ws;
    size_t cur = 0;
    float*  u_ws = (float*)(ws + cur);  cur += (size_t)M_TOT * HH * 4;        // 4 MB
    float*  w_ws = (float*)(ws + cur);  cur += (size_t)M_TOT * HH * 4;        // 4 MB
    bf16_t* Ah   = (bf16_t*)(ws + cur); cur += (size_t)M_TOT * KP * 2;        // 2.25 MB
    bf16_t* Al   = (bf16_t*)(ws + cur); cur += (size_t)M_TOT * KP * 2;
    bf16_t* Buh  = (bf16_t*)(ws + cur); cur += (size_t)HH * KP * 2;           // 0.56 MB
    bf16_t* Bul  = (bf16_t*)(ws + cur); cur += (size_t)HH * KP * 2;
    bf16_t* Bwh  = (bf16_t*)(ws + cur); cur += (size_t)HH * KP * 2;
    bf16_t* Bwl  = (bf16_t*)(ws + cur); cur += (size_t)HH * KP * 2;
    float*  ce_ws = (float*)(ws + cur);                                       // 8 KB

    split_kernel<<<dim3(1440), dim3(256), 0, stream>>>(
        repr, labels, u_w, w_w, Ah, Al, Buh, Bul, Bwh, Bwl);
    gemm_mfma<<<dim3(256), dim3(256), 0, stream>>>(
        Ah, Al, Buh, Bul, Bwh, Bwl, u_b, w_b, u_ws, w_ws);
    scores_v2<<<dim3(512), dim3(256), 0, stream>>>(
        u_ws, w_ws, v_w, heads, words, out, ce_ws);
    loss_sum<<<dim3(1), dim3(256), 0, stream>>>(ce_ws, out);
}